// Round 1
// baseline (206.754 us; speedup 1.0000x reference)
//
#include <hip/hip_runtime.h>

#define HIDDEN 64

// ws layout: dinv[N], agg[N], h2[N]  (3*N floats = 1.2 MB)

__global__ void k_init(float* dinv, float* agg, int n) {
    int i = blockIdx.x * blockDim.x + threadIdx.x;
    if (i < n) { dinv[i] = 1.0f; agg[i] = 0.0f; }  // deg starts at 1 (self-loop)
}

__global__ void k_deg(const int* __restrict__ dst, float* deg, int e) {
    int i = blockIdx.x * blockDim.x + threadIdx.x;
    if (i < e) atomicAdd(&deg[dst[i]], 1.0f);
}

__global__ void k_rsqrt(float* dinv, int n) {
    int i = blockIdx.x * blockDim.x + threadIdx.x;
    if (i < n) dinv[i] = rsqrtf(dinv[i]);  // deg >= 1 always (self-loop)
}

// agg[d] += val[s] * dinv[s]  for every edge s->d
__global__ void k_scatter(const int* __restrict__ src, const int* __restrict__ dst,
                          const float* __restrict__ val, const float* __restrict__ dinv,
                          float* agg, int e) {
    int i = blockIdx.x * blockDim.x + threadIdx.x;
    if (i < e) {
        int s = src[i];
        int d = dst[i];
        atomicAdd(&agg[d], val[s] * dinv[s]);
    }
}

// s1 = dinv*(agg + x*dinv);  h2 = sum_j relu(s1*W1[j]+b1[j])*W2[j];  agg reset to 0
__global__ void k_mlp(const float* __restrict__ x, const float* __restrict__ dinv,
                      float* agg, const float* __restrict__ W1, const float* __restrict__ b1,
                      const float* __restrict__ W2, float* __restrict__ h2, int n) {
    __shared__ float sW1[HIDDEN], sb1[HIDDEN], sW2[HIDDEN];
    if (threadIdx.x < HIDDEN) {
        sW1[threadIdx.x] = W1[threadIdx.x];
        sb1[threadIdx.x] = b1[threadIdx.x];
        sW2[threadIdx.x] = W2[threadIdx.x];
    }
    __syncthreads();
    int i = blockIdx.x * blockDim.x + threadIdx.x;
    if (i < n) {
        float di = dinv[i];
        float s1 = di * (agg[i] + x[i] * di);  // self-loop contribution x[i]*dinv[i]
        agg[i] = 0.0f;                         // reset accumulator for layer 2
        float acc = 0.0f;
#pragma unroll
        for (int j = 0; j < HIDDEN; ++j) {
            acc += fmaxf(fmaf(s1, sW1[j], sb1[j]), 0.0f) * sW2[j];
        }
        h2[i] = acc;
    }
}

__global__ void k_out(const float* __restrict__ h2, const float* __restrict__ dinv,
                      const float* __restrict__ agg, const float* __restrict__ b2,
                      float* __restrict__ out, int n) {
    int i = blockIdx.x * blockDim.x + threadIdx.x;
    if (i < n) {
        float di = dinv[i];
        out[i] = di * (agg[i] + h2[i] * di) + b2[0];
    }
}

extern "C" void kernel_launch(void* const* d_in, const int* in_sizes, int n_in,
                              void* d_out, int out_size, void* d_ws, size_t ws_size,
                              hipStream_t stream) {
    const float* x  = (const float*)d_in[0];
    const int*   ei = (const int*)d_in[1];   // [2, E] int32
    const float* W1 = (const float*)d_in[2];
    const float* b1 = (const float*)d_in[3];
    const float* W2 = (const float*)d_in[4];
    const float* b2 = (const float*)d_in[5];
    float* out = (float*)d_out;

    const int n = in_sizes[0];          // 100000 nodes (x is [N,1])
    const int e = in_sizes[1] / 2;      // 1200000 edges
    const int* src = ei;
    const int* dst = ei + e;

    float* dinv = (float*)d_ws;
    float* agg  = dinv + n;
    float* h2   = agg + n;

    const int BT = 256;
    const int gn = (n + BT - 1) / BT;
    const int ge = (e + BT - 1) / BT;

    k_init<<<gn, BT, 0, stream>>>(dinv, agg, n);
    k_deg<<<ge, BT, 0, stream>>>(dst, dinv, e);
    k_rsqrt<<<gn, BT, 0, stream>>>(dinv, n);
    k_scatter<<<ge, BT, 0, stream>>>(src, dst, x, dinv, agg, e);
    k_mlp<<<gn, BT, 0, stream>>>(x, dinv, agg, W1, b1, W2, h2, n);
    k_scatter<<<ge, BT, 0, stream>>>(src, dst, h2, dinv, agg, e);
    k_out<<<gn, BT, 0, stream>>>(h2, dinv, agg, b2, out, n);
}

// Round 2
// 202.503 us; speedup vs baseline: 1.0210x; 1.0210x over previous
//
#include <hip/hip_runtime.h>

#define HIDDEN 64
#define NREP 8   // one accumulator copy per XCD

// L2-local float atomic add: no sc0/sc1 -> executes in the issuing XCD's L2.
// Only coherent within one XCD; we guarantee each copy is touched by exactly
// one XCD via HW_REG_XCC_ID indexing. Kernel-boundary release flushes L2s.
__device__ __forceinline__ void atomic_add_l2(float* p, float v) {
    asm volatile("global_atomic_add_f32 %0, %1, off" :: "v"(p), "v"(v) : "memory");
}

__device__ __forceinline__ int xcc_id() {
    unsigned x;
    asm("s_getreg_b32 %0, hwreg(HW_REG_XCC_ID)" : "=s"(x));
    return (int)(x & (NREP - 1));
}

__global__ void k_zero(float* p, int m) {
    int i = blockIdx.x * blockDim.x + threadIdx.x;
    int i4 = i * 4;
    if (i4 + 3 < m) {
        *(float4*)(p + i4) = make_float4(0.f, 0.f, 0.f, 0.f);
    } else {
        for (int j = i4; j < m; ++j) p[j] = 0.f;
    }
}

// deg count: acc[copy][dst[i]] += 1
template <int R>
__global__ void k_deg(const int* __restrict__ dst, float* acc, int n, int e) {
    int t = blockIdx.x * blockDim.x + threadIdx.x;
    float* a = acc + (R > 1 ? (size_t)xcc_id() * n : 0);
    int i0 = t * 4;
    if (i0 + 3 < e) {
        int4 d4 = *(const int4*)(dst + i0);
        if (R > 1) {
            atomic_add_l2(&a[d4.x], 1.0f);
            atomic_add_l2(&a[d4.y], 1.0f);
            atomic_add_l2(&a[d4.z], 1.0f);
            atomic_add_l2(&a[d4.w], 1.0f);
        } else {
            atomicAdd(&a[d4.x], 1.0f);
            atomicAdd(&a[d4.y], 1.0f);
            atomicAdd(&a[d4.z], 1.0f);
            atomicAdd(&a[d4.w], 1.0f);
        }
    } else {
        for (int i = i0; i < e; ++i) {
            if (R > 1) atomic_add_l2(&a[dst[i]], 1.0f);
            else       atomicAdd(&a[dst[i]], 1.0f);
        }
    }
}

// dinv = rsqrt(1 + sum_k acc[k][i]); xs = x*dinv; zero acc
template <int R>
__global__ void k_prep(const float* __restrict__ x, float* acc,
                       float* __restrict__ dinv, float* __restrict__ xs, int n) {
    int i = blockIdx.x * blockDim.x + threadIdx.x;
    if (i < n) {
        float s = 1.0f;  // self-loop
#pragma unroll
        for (int k = 0; k < R; ++k) {
            size_t o = (size_t)k * n + i;
            s += acc[o];
            acc[o] = 0.0f;
        }
        float d = rsqrtf(s);
        dinv[i] = d;
        xs[i] = x[i] * d;
    }
}

// acc[copy][dst] += vals[src]   (vals already pre-scaled by dinv[src])
template <int R>
__global__ void k_scatter(const int* __restrict__ src, const int* __restrict__ dst,
                          const float* __restrict__ vals, float* acc, int n, int e) {
    int t = blockIdx.x * blockDim.x + threadIdx.x;
    float* a = acc + (R > 1 ? (size_t)xcc_id() * n : 0);
    int i0 = t * 4;
    if (i0 + 3 < e) {
        int4 s4 = *(const int4*)(src + i0);
        int4 d4 = *(const int4*)(dst + i0);
        float v0 = vals[s4.x], v1 = vals[s4.y], v2 = vals[s4.z], v3 = vals[s4.w];
        if (R > 1) {
            atomic_add_l2(&a[d4.x], v0);
            atomic_add_l2(&a[d4.y], v1);
            atomic_add_l2(&a[d4.z], v2);
            atomic_add_l2(&a[d4.w], v3);
        } else {
            atomicAdd(&a[d4.x], v0);
            atomicAdd(&a[d4.y], v1);
            atomicAdd(&a[d4.z], v2);
            atomicAdd(&a[d4.w], v3);
        }
    } else {
        for (int i = i0; i < e; ++i) {
            float v = vals[src[i]];
            if (R > 1) atomic_add_l2(&a[dst[i]], v);
            else       atomicAdd(&a[dst[i]], v);
        }
    }
}

// s1 = dinv*(sum_k acc + xs); h2s = dinv * sum_j relu(s1*W1[j]+b1[j])*W2[j]; zero acc
template <int R>
__global__ void k_mlp(const float* __restrict__ dinv, const float* __restrict__ xs,
                      float* acc, const float* __restrict__ W1, const float* __restrict__ b1,
                      const float* __restrict__ W2, float* __restrict__ h2s, int n) {
    __shared__ float sW1[HIDDEN], sb1[HIDDEN], sW2[HIDDEN];
    if (threadIdx.x < HIDDEN) {
        sW1[threadIdx.x] = W1[threadIdx.x];
        sb1[threadIdx.x] = b1[threadIdx.x];
        sW2[threadIdx.x] = W2[threadIdx.x];
    }
    __syncthreads();
    int i = blockIdx.x * blockDim.x + threadIdx.x;
    if (i < n) {
        float s = xs[i];  // self-loop term (already x*dinv)
#pragma unroll
        for (int k = 0; k < R; ++k) {
            size_t o = (size_t)k * n + i;
            s += acc[o];
            acc[o] = 0.0f;
        }
        float di = dinv[i];
        float s1 = di * s;
        float h = 0.0f;
#pragma unroll
        for (int j = 0; j < HIDDEN; ++j)
            h += fmaxf(fmaf(s1, sW1[j], sb1[j]), 0.0f) * sW2[j];
        h2s[i] = h * di;
    }
}

template <int R>
__global__ void k_out(const float* __restrict__ dinv, const float* __restrict__ h2s,
                      const float* __restrict__ acc, const float* __restrict__ b2,
                      float* __restrict__ out, int n) {
    int i = blockIdx.x * blockDim.x + threadIdx.x;
    if (i < n) {
        float s = h2s[i];  // self-loop term
#pragma unroll
        for (int k = 0; k < R; ++k) s += acc[(size_t)k * n + i];
        out[i] = dinv[i] * s + b2[0];
    }
}

extern "C" void kernel_launch(void* const* d_in, const int* in_sizes, int n_in,
                              void* d_out, int out_size, void* d_ws, size_t ws_size,
                              hipStream_t stream) {
    const float* x  = (const float*)d_in[0];
    const int*   ei = (const int*)d_in[1];   // [2, E] int32
    const float* W1 = (const float*)d_in[2];
    const float* b1 = (const float*)d_in[3];
    const float* W2 = (const float*)d_in[4];
    const float* b2 = (const float*)d_in[5];
    float* out = (float*)d_out;

    const int n = in_sizes[0];
    const int e = in_sizes[1] / 2;
    const int* src = ei;
    const int* dst = ei + e;

    const int BT = 256;
    const int gn = (n + BT - 1) / BT;
    const int ge4 = ((e + 3) / 4 + BT - 1) / BT;

    const size_t need8 = (size_t)(3 + NREP) * n * sizeof(float);
    if (ws_size >= need8) {
        float* dinv = (float*)d_ws;
        float* xs   = dinv + n;
        float* h2s  = xs + n;
        float* acc  = h2s + n;   // [NREP][n]
        const int m = NREP * n;
        k_zero<<<(m / 4 + BT - 1) / BT, BT, 0, stream>>>(acc, m);
        k_deg<NREP><<<ge4, BT, 0, stream>>>(dst, acc, n, e);
        k_prep<NREP><<<gn, BT, 0, stream>>>(x, acc, dinv, xs, n);
        k_scatter<NREP><<<ge4, BT, 0, stream>>>(src, dst, xs, acc, n, e);
        k_mlp<NREP><<<gn, BT, 0, stream>>>(dinv, xs, acc, W1, b1, W2, h2s, n);
        k_scatter<NREP><<<ge4, BT, 0, stream>>>(src, dst, h2s, acc, n, e);
        k_out<NREP><<<gn, BT, 0, stream>>>(dinv, h2s, acc, b2, out, n);
    } else {
        float* dinv = (float*)d_ws;
        float* xs   = dinv + n;
        float* h2s  = xs + n;
        float* acc  = h2s + n;   // [1][n]
        k_zero<<<(n / 4 + BT - 1) / BT, BT, 0, stream>>>(acc, n);
        k_deg<1><<<ge4, BT, 0, stream>>>(dst, acc, n, e);
        k_prep<1><<<gn, BT, 0, stream>>>(x, acc, dinv, xs, n);
        k_scatter<1><<<ge4, BT, 0, stream>>>(src, dst, xs, acc, n, e);
        k_mlp<1><<<gn, BT, 0, stream>>>(dinv, xs, acc, W1, b1, W2, h2s, n);
        k_scatter<1><<<ge4, BT, 0, stream>>>(src, dst, h2s, acc, n, e);
        k_out<1><<<gn, BT, 0, stream>>>(dinv, h2s, acc, b2, out, n);
    }
}

// Round 3
// 116.393 us; speedup vs baseline: 1.7763x; 1.7398x over previous
//
#include <hip/hip_runtime.h>

#define HIDDEN 64
#define NB 4          // destination buckets
#define BS 25000      // nodes per bucket -> 100 KB LDS
#define NT 1024       // threads per bucketed block
#define MAXBPB 64     // max replicas (slices) per bucket

// ---------------- bucketed LDS-aggregation path (no global atomics) -------

// racc layout: racc[((size_t)g*bpb + b)*BS + li]

__global__ __launch_bounds__(NT) void k_deg_b(const int* __restrict__ dst,
                                              float* __restrict__ racc,
                                              int e, int bpb) {
    __shared__ float lacc[BS];
    const int g = blockIdx.x;          // bucket
    const int b = blockIdx.y;          // edge slice / replica id
    const int base = g * BS;
    for (int i = threadIdx.x; i < BS; i += NT) lacc[i] = 0.0f;
    __syncthreads();
    const int lo = (int)((long)e * b / bpb);
    const int hi = (int)((long)e * (b + 1) / bpb);
    for (int i = lo + threadIdx.x; i < hi; i += NT) {
        int d = dst[i] - base;
        if ((unsigned)d < (unsigned)BS) atomicAdd(&lacc[d], 1.0f);  // ds_add_f32
    }
    __syncthreads();
    float* out = racc + ((size_t)g * bpb + b) * BS;
    for (int i = threadIdx.x; i < BS; i += NT) out[i] = lacc[i];
}

__global__ __launch_bounds__(NT) void k_scat_b(const int* __restrict__ src,
                                               const int* __restrict__ dst,
                                               const float* __restrict__ vals,
                                               float* __restrict__ racc,
                                               int e, int bpb) {
    __shared__ float lacc[BS];
    const int g = blockIdx.x;
    const int b = blockIdx.y;
    const int base = g * BS;
    for (int i = threadIdx.x; i < BS; i += NT) lacc[i] = 0.0f;
    __syncthreads();
    const int lo = (int)((long)e * b / bpb);
    const int hi = (int)((long)e * (b + 1) / bpb);
    for (int i = lo + threadIdx.x; i < hi; i += NT) {
        int d = dst[i] - base;
        if ((unsigned)d < (unsigned)BS) {
            atomicAdd(&lacc[d], vals[src[i]]);
        }
    }
    __syncthreads();
    float* out = racc + ((size_t)g * bpb + b) * BS;
    for (int i = threadIdx.x; i < BS; i += NT) out[i] = lacc[i];
}

// dinv = rsqrt(1 + sum_b racc); xs = x * dinv
__global__ void k_prep(const float* __restrict__ x, const float* __restrict__ racc,
                       float* __restrict__ dinv, float* __restrict__ xs,
                       int n, int bpb) {
    int i = blockIdx.x * blockDim.x + threadIdx.x;
    if (i >= n) return;
    int g = i / BS, li = i - g * BS;
    const float* r = racc + ((size_t)g * bpb) * BS + li;
    float s = 1.0f;  // self-loop
    for (int b = 0; b < bpb; ++b) s += r[(size_t)b * BS];
    float d = rsqrtf(s);
    dinv[i] = d;
    xs[i] = x[i] * d;
}

// s1 = dinv*(sum racc + xs); h2s = dinv * sum_j relu(s1*W1[j]+b1[j])*W2[j]
__global__ void k_mlp(const float* __restrict__ dinv, const float* __restrict__ xs,
                      const float* __restrict__ racc,
                      const float* __restrict__ W1, const float* __restrict__ b1,
                      const float* __restrict__ W2, float* __restrict__ h2s,
                      int n, int bpb) {
    __shared__ float sW1[HIDDEN], sb1[HIDDEN], sW2[HIDDEN];
    if (threadIdx.x < HIDDEN) {
        sW1[threadIdx.x] = W1[threadIdx.x];
        sb1[threadIdx.x] = b1[threadIdx.x];
        sW2[threadIdx.x] = W2[threadIdx.x];
    }
    __syncthreads();
    int i = blockIdx.x * blockDim.x + threadIdx.x;
    if (i >= n) return;
    int g = i / BS, li = i - g * BS;
    const float* r = racc + ((size_t)g * bpb) * BS + li;
    float s = xs[i];
    for (int b = 0; b < bpb; ++b) s += r[(size_t)b * BS];
    float di = dinv[i];
    float s1 = di * s;
    float h = 0.0f;
#pragma unroll
    for (int j = 0; j < HIDDEN; ++j)
        h += fmaxf(fmaf(s1, sW1[j], sb1[j]), 0.0f) * sW2[j];
    h2s[i] = h * di;
}

__global__ void k_out(const float* __restrict__ dinv, const float* __restrict__ h2s,
                      const float* __restrict__ racc, const float* __restrict__ b2,
                      float* __restrict__ out, int n, int bpb) {
    int i = blockIdx.x * blockDim.x + threadIdx.x;
    if (i >= n) return;
    int g = i / BS, li = i - g * BS;
    const float* r = racc + ((size_t)g * bpb) * BS + li;
    float s = h2s[i];
    for (int b = 0; b < bpb; ++b) s += r[(size_t)b * BS];
    out[i] = dinv[i] * s + b2[0];
}

// ---------------- fallback: single-copy global-atomic path ----------------

__global__ void f_init(float* deg, float* agg, int n) {
    int i = blockIdx.x * blockDim.x + threadIdx.x;
    if (i < n) { deg[i] = 1.0f; agg[i] = 0.0f; }
}
__global__ void f_deg(const int* __restrict__ dst, float* deg, int e) {
    int i = blockIdx.x * blockDim.x + threadIdx.x;
    if (i < e) atomicAdd(&deg[dst[i]], 1.0f);
}
__global__ void f_prep(const float* __restrict__ x, float* deg,
                       float* __restrict__ xs, int n) {
    int i = blockIdx.x * blockDim.x + threadIdx.x;
    if (i < n) { float d = rsqrtf(deg[i]); deg[i] = d; xs[i] = x[i] * d; }
}
__global__ void f_scat(const int* __restrict__ src, const int* __restrict__ dst,
                       const float* __restrict__ vals, float* agg, int e) {
    int i = blockIdx.x * blockDim.x + threadIdx.x;
    if (i < e) atomicAdd(&agg[dst[i]], vals[src[i]]);
}
__global__ void f_mlp(const float* __restrict__ dinv, const float* __restrict__ xs,
                      float* agg, const float* __restrict__ W1,
                      const float* __restrict__ b1, const float* __restrict__ W2,
                      float* __restrict__ h2s, int n) {
    __shared__ float sW1[HIDDEN], sb1[HIDDEN], sW2[HIDDEN];
    if (threadIdx.x < HIDDEN) {
        sW1[threadIdx.x] = W1[threadIdx.x];
        sb1[threadIdx.x] = b1[threadIdx.x];
        sW2[threadIdx.x] = W2[threadIdx.x];
    }
    __syncthreads();
    int i = blockIdx.x * blockDim.x + threadIdx.x;
    if (i >= n) return;
    float di = dinv[i];
    float s1 = di * (agg[i] + xs[i]);
    agg[i] = 0.0f;
    float h = 0.0f;
#pragma unroll
    for (int j = 0; j < HIDDEN; ++j)
        h += fmaxf(fmaf(s1, sW1[j], sb1[j]), 0.0f) * sW2[j];
    h2s[i] = h * di;
}
__global__ void f_out(const float* __restrict__ dinv, const float* __restrict__ h2s,
                      const float* __restrict__ agg, const float* __restrict__ b2,
                      float* __restrict__ out, int n) {
    int i = blockIdx.x * blockDim.x + threadIdx.x;
    if (i < n) out[i] = dinv[i] * (agg[i] + h2s[i]) + b2[0];
}

// ---------------------------------------------------------------------------

extern "C" void kernel_launch(void* const* d_in, const int* in_sizes, int n_in,
                              void* d_out, int out_size, void* d_ws, size_t ws_size,
                              hipStream_t stream) {
    const float* x  = (const float*)d_in[0];
    const int*   ei = (const int*)d_in[1];   // [2, E] int32
    const float* W1 = (const float*)d_in[2];
    const float* b1 = (const float*)d_in[3];
    const float* W2 = (const float*)d_in[4];
    const float* b2 = (const float*)d_in[5];
    float* out = (float*)d_out;

    const int n = in_sizes[0];
    const int e = in_sizes[1] / 2;
    const int* src = ei;
    const int* dst = ei + e;

    const int BT = 256;
    const int gn = (n + BT - 1) / BT;

    // workspace: dinv[n], xs[n], h2s[n], racc[NB*bpb*BS]
    size_t avail_f = ws_size / sizeof(float);
    long bpb_l = ((long)avail_f - 3L * n) / ((long)NB * BS);
    int bpb = (int)(bpb_l < 0 ? 0 : bpb_l);
    if (bpb > MAXBPB) bpb = MAXBPB;

    if (bpb >= 4 && n <= NB * BS) {
        float* dinv = (float*)d_ws;
        float* xs   = dinv + n;
        float* h2s  = xs + n;
        float* racc = h2s + n;

        dim3 gb(NB, bpb);
        k_deg_b <<<gb, NT, 0, stream>>>(dst, racc, e, bpb);
        k_prep  <<<gn, BT, 0, stream>>>(x, racc, dinv, xs, n, bpb);
        k_scat_b<<<gb, NT, 0, stream>>>(src, dst, xs, racc, e, bpb);
        k_mlp   <<<gn, BT, 0, stream>>>(dinv, xs, racc, W1, b1, W2, h2s, n, bpb);
        k_scat_b<<<gb, NT, 0, stream>>>(src, dst, h2s, racc, e, bpb);
        k_out   <<<gn, BT, 0, stream>>>(dinv, h2s, racc, b2, out, n, bpb);
    } else {
        // fallback: single-copy atomic path
        const int ge = (e + BT - 1) / BT;
        float* dinv = (float*)d_ws;   // holds deg then dinv
        float* xs   = dinv + n;
        float* h2s  = xs + n;
        float* agg  = h2s + n;
        f_init<<<gn, BT, 0, stream>>>(dinv, agg, n);
        f_deg <<<ge, BT, 0, stream>>>(dst, dinv, e);
        f_prep<<<gn, BT, 0, stream>>>(x, dinv, xs, n);
        f_scat<<<ge, BT, 0, stream>>>(src, dst, xs, agg, e);
        f_mlp <<<gn, BT, 0, stream>>>(dinv, xs, agg, W1, b1, W2, h2s, n);
        f_scat<<<ge, BT, 0, stream>>>(src, dst, h2s, agg, e);
        f_out <<<gn, BT, 0, stream>>>(dinv, h2s, agg, b2, out, n);
    }
}